// Round 13
// baseline (125.623 us; speedup 1.0000x reference)
//
#include <hip/hip_runtime.h>
#include <hip/hip_bf16.h>

#define NN 50000
#define EE 600000
#define DD 128
#define CAP 48            // max in-degree capacity (actual max ~28)
#define CNT_SHIFT 25      // cnt32: count in [25:31], sum(ew) 2^-16 fixed in [0:24]
#define SUM_MASK 0x1FFFFFFu

#define HF_BLOCKS ((EE + 255) / 256)          // 2344 histfill blocks
#define XC_BLOCKS (NN * DD / 8 / 256)         // 3125 x->bf16 blocks

typedef __attribute__((ext_vector_type(8))) __bf16 bf16x8;
typedef __attribute__((ext_vector_type(8))) short short8;
typedef __attribute__((ext_vector_type(4))) float f32x4;

__device__ __forceinline__ unsigned short f2bf(float f) {
    union { float f; unsigned u; } c; c.f = f;
    unsigned r = (c.u + 0x7fffu + ((c.u >> 16) & 1u)) >> 16;
    return (unsigned short)r;
}
__device__ __forceinline__ float bflo(unsigned u) {
    union { unsigned u; float f; } c; c.u = u << 16; return c.f;
}
__device__ __forceinline__ float bfhi(unsigned u) {
    union { unsigned u; float f; } c; c.u = u & 0xffff0000u; return c.f;
}
__device__ __forceinline__ float degof(unsigned p) {
    return 1.0f + (float)(p & SUM_MASK) * (1.0f / 65536.0f);  // +1 self loop
}

// ---- K1: clear(cnt32) + GRU(W0 -> bf16 W^T) + Wlin -> bf16 ----
// blocks [0,49): zero cnt32.  [49,113): GRU.  [113,177): Wlin conv.
__global__ __launch_bounds__(256) void init_kernel(
    unsigned* __restrict__ cnt32,
    const float* __restrict__ W0, const float* __restrict__ w_ih,
    const float* __restrict__ w_hh, const float* __restrict__ b_ih,
    const float* __restrict__ b_hh, unsigned short* __restrict__ Wbt,
    const float* __restrict__ Wlin, unsigned short* __restrict__ Wlbt)
{
    if (blockIdx.x < 49) {                         // clear cnt32
        int i = blockIdx.x * 256 + threadIdx.x;
        if (i < 50176 * 4 / 16) ((uint4*)cnt32)[i] = make_uint4(0u, 0u, 0u, 0u);
        return;
    }
    if (blockIdx.x >= 113) {                       // Wlin fp32 -> bf16 (layout kept)
        int idx = (blockIdx.x - 113) * 256 + threadIdx.x;   // 0..16383
        Wlbt[idx] = f2bf(Wlin[idx]);
        return;
    }
    int idx = (blockIdx.x - 49) * 256 + threadIdx.x;   // GRU: 0 .. 16383
    int i = idx >> 7, j = idx & 127;                   // i = k index, j = col
    const float4* a  = (const float4*)(W0  + i * DD);
    const float4* pr = (const float4*)(w_ih + (j        ) * DD);
    const float4* pz = (const float4*)(w_ih + (j + 128  ) * DD);
    const float4* pn = (const float4*)(w_ih + (j + 256  ) * DD);
    const float4* qr = (const float4*)(w_hh + (j        ) * DD);
    const float4* qz = (const float4*)(w_hh + (j + 128  ) * DD);
    const float4* qn = (const float4*)(w_hh + (j + 256  ) * DD);
    float ir = 0.f, iz = 0.f, inn = 0.f, hr = 0.f, hz = 0.f, hn = 0.f;
    for (int d = 0; d < DD / 4; ++d) {
        float4 av = a[d];
        float4 t;
        t = pr[d]; ir  += av.x*t.x + av.y*t.y + av.z*t.z + av.w*t.w;
        t = pz[d]; iz  += av.x*t.x + av.y*t.y + av.z*t.z + av.w*t.w;
        t = pn[d]; inn += av.x*t.x + av.y*t.y + av.z*t.z + av.w*t.w;
        t = qr[d]; hr  += av.x*t.x + av.y*t.y + av.z*t.z + av.w*t.w;
        t = qz[d]; hz  += av.x*t.x + av.y*t.y + av.z*t.z + av.w*t.w;
        t = qn[d]; hn  += av.x*t.x + av.y*t.y + av.z*t.z + av.w*t.w;
    }
    ir += b_ih[j]; iz += b_ih[j + 128]; inn += b_ih[j + 256];
    hr += b_hh[j]; hz += b_hh[j + 128]; hn  += b_hh[j + 256];
    float r = 1.f / (1.f + expf(-(ir + hr)));
    float z = 1.f / (1.f + expf(-(iz + hz)));
    float n = tanhf(inn + r * hn);
    float w = (1.f - z) * n + z * W0[idx];
    Wbt[j * DD + i] = f2bf(w);   // transposed: Bt[col][k]
}

// ---- K2: histfill (blocks [0,HF_BLOCKS)) || x->bf16 (blocks [HF_BLOCKS,..)) ----
// Independent subtasks co-scheduled: atomic-bound histfill leaves memory BW
// idle; the BW-bound x conversion rides under it.
__global__ __launch_bounds__(256) void hf_conv_kernel(
    const int* __restrict__ row, const int* __restrict__ col,
    const float* __restrict__ ew,
    unsigned* __restrict__ cnt32, unsigned* __restrict__ edges,
    const float* __restrict__ x, short* __restrict__ xb)
{
    if (blockIdx.x < HF_BLOCKS) {
        int e = blockIdx.x * 256 + threadIdx.x;
        if (e < EE) {
            int c = col[e];
            unsigned wq = (unsigned)(ew[e] * 65536.0f);   // 16-bit fixed ew
            if (wq > 65535u) wq = 65535u;
            unsigned old = atomicAdd(&cnt32[c], (1u << CNT_SHIFT) | wq);
            unsigned oldcnt = old >> CNT_SHIFT;
            if (oldcnt < CAP)
                edges[(size_t)c * CAP + oldcnt] = (unsigned)row[e] | (wq << 16);
        }
        return;
    }
    int u = (blockIdx.x - HF_BLOCKS) * 256 + threadIdx.x;   // 0 .. 799999
    const float4* p = (const float4*)x + (size_t)u * 2;
    float4 f0 = p[0], f1 = p[1];
    short8 v;
    v[0] = (short)f2bf(f0.x); v[1] = (short)f2bf(f0.y);
    v[2] = (short)f2bf(f0.z); v[3] = (short)f2bf(f0.w);
    v[4] = (short)f2bf(f1.x); v[5] = (short)f2bf(f1.y);
    v[6] = (short)f2bf(f1.z); v[7] = (short)f2bf(f1.w);
    *(short8*)(xb + (size_t)u * 8) = v;
}

// -------- gather: 2 nodes per wave, interleaved 4-edge batches --------
__global__ __launch_bounds__(256) void gather_kernel(
    const unsigned* __restrict__ edges, const unsigned* __restrict__ cnt32,
    const unsigned* __restrict__ xbu, unsigned* __restrict__ aggu)
{
    int wid  = threadIdx.x >> 6;           // 4 waves per block
    int lane = threadIdx.x & 63;
    int base = (blockIdx.x * 4 + wid) * 2; // nodes base, base+1
    if (base >= NN) return;
    bool hasB = (base + 1) < NN;

    unsigned pnA = cnt32[base];
    unsigned pnB = hasB ? cnt32[base + 1] : 0u;
    int nA = (int)(pnA >> CNT_SHIFT); if (nA > CAP) nA = CAP;
    int nB = hasB ? (int)(pnB >> CNT_SHIFT) : 0; if (nB > CAP) nB = CAP;
    const unsigned* ebA = edges + (size_t)base * CAP;
    const unsigned* ebB = edges + (size_t)(base + 1) * CAP;
    float sclA = rsqrtf(degof(pnA));
    float sclB = hasB ? rsqrtf(degof(pnB)) : 0.f;
    unsigned xsA = xbu[(size_t)base * 64 + lane];
    unsigned xsB = hasB ? xbu[(size_t)(base + 1) * 64 + lane] : 0u;
    float axA = sclA * bflo(xsA), ayA = sclA * bfhi(xsA);  // self loop
    float axB = sclB * bflo(xsB), ayB = sclB * bfhi(xsB);

    int kA = 0, kB = 0;
    int nA4 = nA & ~3, nB4 = nB & ~3;
    while (kA < nA4 || kB < nB4) {        // wave-uniform conditions
        if (kA < nA4) {
            uint4 rc = *(const uint4*)(ebA + kA);
            int s0 = (int)(rc.x & 0xFFFFu), s1 = (int)(rc.y & 0xFFFFu);
            int s2 = (int)(rc.z & 0xFFFFu), s3 = (int)(rc.w & 0xFFFFu);
            unsigned p0 = cnt32[s0], p1 = cnt32[s1], p2 = cnt32[s2], p3 = cnt32[s3];
            unsigned x0 = xbu[(size_t)s0 * 64 + lane];
            unsigned x1 = xbu[(size_t)s1 * 64 + lane];
            unsigned x2 = xbu[(size_t)s2 * 64 + lane];
            unsigned x3 = xbu[(size_t)s3 * 64 + lane];
            float v0 = (float)(rc.x >> 16) * (1.0f / 65536.0f) * rsqrtf(degof(p0));
            float v1 = (float)(rc.y >> 16) * (1.0f / 65536.0f) * rsqrtf(degof(p1));
            float v2 = (float)(rc.z >> 16) * (1.0f / 65536.0f) * rsqrtf(degof(p2));
            float v3 = (float)(rc.w >> 16) * (1.0f / 65536.0f) * rsqrtf(degof(p3));
            axA += v0 * bflo(x0) + v1 * bflo(x1) + v2 * bflo(x2) + v3 * bflo(x3);
            ayA += v0 * bfhi(x0) + v1 * bfhi(x1) + v2 * bfhi(x2) + v3 * bfhi(x3);
            kA += 4;
        }
        if (kB < nB4) {
            uint4 rc = *(const uint4*)(ebB + kB);
            int s0 = (int)(rc.x & 0xFFFFu), s1 = (int)(rc.y & 0xFFFFu);
            int s2 = (int)(rc.z & 0xFFFFu), s3 = (int)(rc.w & 0xFFFFu);
            unsigned p0 = cnt32[s0], p1 = cnt32[s1], p2 = cnt32[s2], p3 = cnt32[s3];
            unsigned x0 = xbu[(size_t)s0 * 64 + lane];
            unsigned x1 = xbu[(size_t)s1 * 64 + lane];
            unsigned x2 = xbu[(size_t)s2 * 64 + lane];
            unsigned x3 = xbu[(size_t)s3 * 64 + lane];
            float v0 = (float)(rc.x >> 16) * (1.0f / 65536.0f) * rsqrtf(degof(p0));
            float v1 = (float)(rc.y >> 16) * (1.0f / 65536.0f) * rsqrtf(degof(p1));
            float v2 = (float)(rc.z >> 16) * (1.0f / 65536.0f) * rsqrtf(degof(p2));
            float v3 = (float)(rc.w >> 16) * (1.0f / 65536.0f) * rsqrtf(degof(p3));
            axB += v0 * bflo(x0) + v1 * bflo(x1) + v2 * bflo(x2) + v3 * bflo(x3);
            ayB += v0 * bfhi(x0) + v1 * bfhi(x1) + v2 * bfhi(x2) + v3 * bfhi(x3);
            kB += 4;
        }
    }
    for (; kA < nA; ++kA) {
        unsigned r0 = ebA[kA];
        int s0 = (int)(r0 & 0xFFFFu);
        unsigned p0 = cnt32[s0];
        unsigned x0 = xbu[(size_t)s0 * 64 + lane];
        float v0 = (float)(r0 >> 16) * (1.0f / 65536.0f) * rsqrtf(degof(p0));
        axA += v0 * bflo(x0); ayA += v0 * bfhi(x0);
    }
    for (; kB < nB; ++kB) {
        unsigned r0 = ebB[kB];
        int s0 = (int)(r0 & 0xFFFFu);
        unsigned p0 = cnt32[s0];
        unsigned x0 = xbu[(size_t)s0 * 64 + lane];
        float v0 = (float)(r0 >> 16) * (1.0f / 65536.0f) * rsqrtf(degof(p0));
        axB += v0 * bflo(x0); ayB += v0 * bfhi(x0);
    }
    aggu[(size_t)base * 64 + lane] =
        (unsigned)f2bf(axA * sclA) | ((unsigned)f2bf(ayA * sclA) << 16);
    if (hasB)
        aggu[(size_t)(base + 1) * 64 + lane] =
            (unsigned)f2bf(axB * sclB) | ((unsigned)f2bf(ayB * sclB) << 16);
}

// ------- fused dual MFMA GEMM: out = relu(agg @ Wbt^T) @ Wlbt^T + bias -------
__global__ __launch_bounds__(256) void fused_gemm(
    const short* __restrict__ agg, const short* __restrict__ Wbt,
    const short* __restrict__ Wlbt, const float* __restrict__ bias,
    float* __restrict__ out)
{
    __shared__ __align__(16) short Bs1[DD * DD];  // Wbt [col][k], 32KB, swizzled
    __shared__ __align__(16) short Bs2[DD * DD];  // Wlbt [col][k], 32KB, swizzled
    __shared__ __align__(16) short As[64 * DD];   // A tile / relu(h) tile, 16KB
    const int t = threadIdx.x;
    const int i0 = blockIdx.x * 64;

    // stage Bs1/Bs2 (bf16 straight copies, swizzled)
    for (int u = t; u < 2048; u += 256) {
        int byte = u << 4;
        int brow = byte >> 8;
        int sw = byte ^ ((brow & 7) << 4);
        *(short8*)((char*)Bs1 + sw) = *(const short8*)((const char*)Wbt + byte);
        *(short8*)((char*)Bs2 + sw) = *(const short8*)((const char*)Wlbt + byte);
    }
    // stage A tile from agg (bf16 straight copy, swizzled; zero-pad tail rows)
    for (int u = t; u < 1024; u += 256) {
        int arow = u >> 4;
        int kc = (u & 15) << 3;
        int grow = i0 + arow;
        short8 v;
#pragma unroll
        for (int i = 0; i < 8; ++i) v[i] = 0;
        if (grow < NN)
            v = *(const short8*)(agg + (size_t)grow * DD + kc);
        int byte = (arow << 8) + (kc << 1);
        *(short8*)((char*)As + (byte ^ ((arow & 7) << 4))) = v;
    }
    __syncthreads();

    const int lane = t & 63, wv = t >> 6;
    const int c0 = lane & 15, g = lane >> 4;
    const int arow = wv * 16 + c0;
    f32x4 acc[8];
#pragma unroll
    for (int n = 0; n < 8; ++n) { acc[n][0] = acc[n][1] = acc[n][2] = acc[n][3] = 0.f; }

    // GEMM1: h = A @ Wbt^T
#pragma unroll
    for (int s = 0; s < 4; ++s) {
        int k0 = s * 32 + g * 8;
        int abyte = (arow << 8) + (k0 << 1);
        bf16x8 a = *(const bf16x8*)((const char*)As + (abyte ^ ((arow & 7) << 4)));
#pragma unroll
        for (int n = 0; n < 8; ++n) {
            int bcol = n * 16 + c0;
            int bbyte = (bcol << 8) + (k0 << 1);
            bf16x8 b = *(const bf16x8*)((const char*)Bs1 + (bbyte ^ ((bcol & 7) << 4)));
            acc[n] = __builtin_amdgcn_mfma_f32_16x16x32_bf16(a, b, acc[n], 0, 0, 0);
        }
    }
    __syncthreads();   // all GEMM1 LDS reads done before As overwrite

    // write relu(h) back into As as bf16 (C/D layout: col=c0+16n, row=wv*16+g*4+r)
#pragma unroll
    for (int n = 0; n < 8; ++n) {
        int ccol = n * 16 + c0;
#pragma unroll
        for (int r = 0; r < 4; ++r) {
            int hrow = wv * 16 + g * 4 + r;
            int byte = (hrow << 8) + (ccol << 1);
            *(unsigned short*)((char*)As + (byte ^ ((hrow & 7) << 4))) =
                f2bf(fmaxf(acc[n][r], 0.f));
        }
    }
    __syncthreads();

#pragma unroll
    for (int n = 0; n < 8; ++n) { acc[n][0] = acc[n][1] = acc[n][2] = acc[n][3] = 0.f; }

    // GEMM2: out = relu(h) @ Wlbt^T
#pragma unroll
    for (int s = 0; s < 4; ++s) {
        int k0 = s * 32 + g * 8;
        int abyte = (arow << 8) + (k0 << 1);
        bf16x8 a = *(const bf16x8*)((const char*)As + (abyte ^ ((arow & 7) << 4)));
#pragma unroll
        for (int n = 0; n < 8; ++n) {
            int bcol = n * 16 + c0;
            int bbyte = (bcol << 8) + (k0 << 1);
            bf16x8 b = *(const bf16x8*)((const char*)Bs2 + (bbyte ^ ((bcol & 7) << 4)));
            acc[n] = __builtin_amdgcn_mfma_f32_16x16x32_bf16(a, b, acc[n], 0, 0, 0);
        }
    }

    // store with bias
#pragma unroll
    for (int n = 0; n < 8; ++n) {
        int ccol = n * 16 + c0;
        float bb = bias[ccol];
#pragma unroll
        for (int r = 0; r < 4; ++r) {
            int grow = i0 + wv * 16 + g * 4 + r;
            if (grow < NN)
                out[(size_t)grow * DD + ccol] = acc[n][r] + bb;
        }
    }
}

extern "C" void kernel_launch(void* const* d_in, const int* in_sizes, int n_in,
                              void* d_out, int out_size, void* d_ws, size_t ws_size,
                              hipStream_t stream)
{
    const float* x    = (const float*)d_in[0];
    const int*   ei   = (const int*)d_in[1];
    const float* ew   = (const float*)d_in[2];
    const float* W0   = (const float*)d_in[3];
    const float* w_ih = (const float*)d_in[4];
    const float* w_hh = (const float*)d_in[5];
    const float* b_ih = (const float*)d_in[6];
    const float* b_hh = (const float*)d_in[7];
    const float* Wlin = (const float*)d_in[8];
    const float* blin = (const float*)d_in[9];
    float* out = (float*)d_out;

    const int* row = ei;        // source
    const int* col = ei + EE;   // target

    // workspace (bytes):
    // Wbt[32768] | Wlbt[32768] | cnt32[200704] | xb[12.8MB] | agg[12.8MB] | edges[9.6MB]
    char* ws = (char*)d_ws;
    unsigned short* Wbt  = (unsigned short*)ws;
    unsigned short* Wlbt = (unsigned short*)(ws + 32768);
    unsigned* cnt32 = (unsigned*)(ws + 65536);
    short* xb   = (short*)(ws + 266240);
    short* agg  = (short*)(ws + 13066240);
    unsigned* edges = (unsigned*)(ws + 25866240);

    init_kernel<<<177, 256, 0, stream>>>(cnt32, W0, w_ih, w_hh, b_ih, b_hh,
                                         Wbt, Wlin, Wlbt);

    hf_conv_kernel<<<HF_BLOCKS + XC_BLOCKS, 256, 0, stream>>>(
        row, col, ew, cnt32, edges, x, xb);

    gather_kernel<<<(NN + 7) / 8, 256, 0, stream>>>(
        edges, cnt32, (const unsigned*)xb, (unsigned*)agg);

    fused_gemm<<<(NN + 63) / 64, 256, 0, stream>>>(
        agg, (const short*)Wbt, (const short*)Wlbt, blin, out);
}

// Round 14
// 117.773 us; speedup vs baseline: 1.0667x; 1.0667x over previous
//
#include <hip/hip_runtime.h>
#include <hip/hip_bf16.h>

#define NN 50000
#define EE 600000
#define DD 128
#define CAP 48            // max in-degree capacity (actual max ~28)
#define CNT_SHIFT 25      // cnt32: count in [25:31], sum(ew) 2^-16 fixed in [0:24]
#define SUM_MASK 0x1FFFFFFu

typedef __attribute__((ext_vector_type(8))) __bf16 bf16x8;
typedef __attribute__((ext_vector_type(8))) short short8;
typedef __attribute__((ext_vector_type(4))) float f32x4;

__device__ __forceinline__ unsigned short f2bf(float f) {
    union { float f; unsigned u; } c; c.f = f;
    unsigned r = (c.u + 0x7fffu + ((c.u >> 16) & 1u)) >> 16;
    return (unsigned short)r;
}
__device__ __forceinline__ float bflo(unsigned u) {
    union { unsigned u; float f; } c; c.u = u << 16; return c.f;
}
__device__ __forceinline__ float bfhi(unsigned u) {
    union { unsigned u; float f; } c; c.u = u & 0xffff0000u; return c.f;
}
__device__ __forceinline__ float degof(unsigned p) {
    return 1.0f + (float)(p & SUM_MASK) * (1.0f / 65536.0f);  // +1 self loop
}

// ---- K0: clear(cnt32) + GRU(W0 -> bf16 W^T) + Wlin -> bf16 + x -> bf16 ----
// blocks [0,49): zero cnt32. [49,113): GRU. [113,177): Wlin conv. [177,3302): x conv.
__global__ __launch_bounds__(256) void init_kernel(
    unsigned* __restrict__ cnt32,
    const float* __restrict__ W0, const float* __restrict__ w_ih,
    const float* __restrict__ w_hh, const float* __restrict__ b_ih,
    const float* __restrict__ b_hh, unsigned short* __restrict__ Wbt,
    const float* __restrict__ Wlin, unsigned short* __restrict__ Wlbt,
    const float* __restrict__ x, short* __restrict__ xb)
{
    if (blockIdx.x >= 177) {                       // x -> bf16 (800000 threads)
        int u = (blockIdx.x - 177) * 256 + threadIdx.x;
        if (u < NN * DD / 8) {
            const float4* p = (const float4*)x + (size_t)u * 2;
            float4 f0 = p[0], f1 = p[1];
            short8 v;
            v[0] = (short)f2bf(f0.x); v[1] = (short)f2bf(f0.y);
            v[2] = (short)f2bf(f0.z); v[3] = (short)f2bf(f0.w);
            v[4] = (short)f2bf(f1.x); v[5] = (short)f2bf(f1.y);
            v[6] = (short)f2bf(f1.z); v[7] = (short)f2bf(f1.w);
            *(short8*)(xb + (size_t)u * 8) = v;
        }
        return;
    }
    if (blockIdx.x < 49) {                         // clear cnt32
        int i = blockIdx.x * 256 + threadIdx.x;
        if (i < 50176 * 4 / 16) ((uint4*)cnt32)[i] = make_uint4(0u, 0u, 0u, 0u);
        return;
    }
    if (blockIdx.x >= 113) {                       // Wlin fp32 -> bf16 (layout kept)
        int idx = (blockIdx.x - 113) * 256 + threadIdx.x;   // 0..16383
        Wlbt[idx] = f2bf(Wlin[idx]);
        return;
    }
    int idx = (blockIdx.x - 49) * 256 + threadIdx.x;   // GRU: 0 .. 16383
    int i = idx >> 7, j = idx & 127;                   // i = k index, j = col
    const float4* a  = (const float4*)(W0  + i * DD);
    const float4* pr = (const float4*)(w_ih + (j        ) * DD);
    const float4* pz = (const float4*)(w_ih + (j + 128  ) * DD);
    const float4* pn = (const float4*)(w_ih + (j + 256  ) * DD);
    const float4* qr = (const float4*)(w_hh + (j        ) * DD);
    const float4* qz = (const float4*)(w_hh + (j + 128  ) * DD);
    const float4* qn = (const float4*)(w_hh + (j + 256  ) * DD);
    float ir = 0.f, iz = 0.f, inn = 0.f, hr = 0.f, hz = 0.f, hn = 0.f;
    for (int d = 0; d < DD / 4; ++d) {
        float4 av = a[d];
        float4 t;
        t = pr[d]; ir  += av.x*t.x + av.y*t.y + av.z*t.z + av.w*t.w;
        t = pz[d]; iz  += av.x*t.x + av.y*t.y + av.z*t.z + av.w*t.w;
        t = pn[d]; inn += av.x*t.x + av.y*t.y + av.z*t.z + av.w*t.w;
        t = qr[d]; hr  += av.x*t.x + av.y*t.y + av.z*t.z + av.w*t.w;
        t = qz[d]; hz  += av.x*t.x + av.y*t.y + av.z*t.z + av.w*t.w;
        t = qn[d]; hn  += av.x*t.x + av.y*t.y + av.z*t.z + av.w*t.w;
    }
    ir += b_ih[j]; iz += b_ih[j + 128]; inn += b_ih[j + 256];
    hr += b_hh[j]; hz += b_hh[j + 128]; hn  += b_hh[j + 256];
    float r = 1.f / (1.f + expf(-(ir + hr)));
    float z = 1.f / (1.f + expf(-(iz + hz)));
    float n = tanhf(inn + r * hn);
    float w = (1.f - z) * n + z * W0[idx];
    Wbt[j * DD + i] = f2bf(w);   // transposed: Bt[col][k]
}

// ---------------- hist+fill: ONE 32-bit atomic per edge (R9 form) ----------------
__global__ __launch_bounds__(256) void histfill_kernel(
    const int* __restrict__ row, const int* __restrict__ col,
    const float* __restrict__ ew,
    unsigned* __restrict__ cnt32, unsigned* __restrict__ edges)
{
    int e = blockIdx.x * 256 + threadIdx.x;
    if (e >= EE) return;
    int c = col[e];
    unsigned wq = (unsigned)(ew[e] * 65536.0f);      // 16-bit fixed ew
    if (wq > 65535u) wq = 65535u;
    unsigned old = atomicAdd(&cnt32[c], (1u << CNT_SHIFT) | wq);
    unsigned oldcnt = old >> CNT_SHIFT;
    if (oldcnt < CAP)
        edges[(size_t)c * CAP + oldcnt] = (unsigned)row[e] | (wq << 16);
}

// ---------------- gather: 8-edge unrolled, one node per wave (R9 form) ----------------
__global__ __launch_bounds__(256) void gather_kernel(
    const unsigned* __restrict__ edges, const unsigned* __restrict__ cnt32,
    const unsigned* __restrict__ xbu, unsigned* __restrict__ aggu)
{
    int wid  = threadIdx.x >> 6;           // 4 waves per block
    int lane = threadIdx.x & 63;
    int node = blockIdx.x * 4 + wid;
    if (node >= NN) return;
    unsigned pn = cnt32[node];
    int n = (int)(pn >> CNT_SHIFT); if (n > CAP) n = CAP;
    const unsigned* eb = edges + (size_t)node * CAP;
    float s = rsqrtf(degof(pn));
    unsigned xs = xbu[(size_t)node * 64 + lane];
    float ax = s * bflo(xs), ay = s * bfhi(xs);   // self-loop (s^2 x total)
    int k = 0;
    int n8 = n & ~7;
    for (; k < n8; k += 8) {
        uint4 ra = *(const uint4*)(eb + k);
        uint4 rb = *(const uint4*)(eb + k + 4);
        int s0 = (int)(ra.x & 0xFFFFu), s1 = (int)(ra.y & 0xFFFFu);
        int s2 = (int)(ra.z & 0xFFFFu), s3 = (int)(ra.w & 0xFFFFu);
        int s4 = (int)(rb.x & 0xFFFFu), s5 = (int)(rb.y & 0xFFFFu);
        int s6 = (int)(rb.z & 0xFFFFu), s7 = (int)(rb.w & 0xFFFFu);
        unsigned p0 = cnt32[s0], p1 = cnt32[s1], p2 = cnt32[s2], p3 = cnt32[s3];
        unsigned p4 = cnt32[s4], p5 = cnt32[s5], p6 = cnt32[s6], p7 = cnt32[s7];
        unsigned x0 = xbu[(size_t)s0 * 64 + lane];
        unsigned x1 = xbu[(size_t)s1 * 64 + lane];
        unsigned x2 = xbu[(size_t)s2 * 64 + lane];
        unsigned x3 = xbu[(size_t)s3 * 64 + lane];
        unsigned x4 = xbu[(size_t)s4 * 64 + lane];
        unsigned x5 = xbu[(size_t)s5 * 64 + lane];
        unsigned x6 = xbu[(size_t)s6 * 64 + lane];
        unsigned x7 = xbu[(size_t)s7 * 64 + lane];
        float v0 = (float)(ra.x >> 16) * (1.0f / 65536.0f) * rsqrtf(degof(p0));
        float v1 = (float)(ra.y >> 16) * (1.0f / 65536.0f) * rsqrtf(degof(p1));
        float v2 = (float)(ra.z >> 16) * (1.0f / 65536.0f) * rsqrtf(degof(p2));
        float v3 = (float)(ra.w >> 16) * (1.0f / 65536.0f) * rsqrtf(degof(p3));
        float v4 = (float)(rb.x >> 16) * (1.0f / 65536.0f) * rsqrtf(degof(p4));
        float v5 = (float)(rb.y >> 16) * (1.0f / 65536.0f) * rsqrtf(degof(p5));
        float v6 = (float)(rb.z >> 16) * (1.0f / 65536.0f) * rsqrtf(degof(p6));
        float v7 = (float)(rb.w >> 16) * (1.0f / 65536.0f) * rsqrtf(degof(p7));
        ax += v0 * bflo(x0) + v1 * bflo(x1) + v2 * bflo(x2) + v3 * bflo(x3)
            + v4 * bflo(x4) + v5 * bflo(x5) + v6 * bflo(x6) + v7 * bflo(x7);
        ay += v0 * bfhi(x0) + v1 * bfhi(x1) + v2 * bfhi(x2) + v3 * bfhi(x3)
            + v4 * bfhi(x4) + v5 * bfhi(x5) + v6 * bfhi(x6) + v7 * bfhi(x7);
    }
    int n4 = n & ~3;
    for (; k < n4; k += 4) {
        uint4 rc = *(const uint4*)(eb + k);
        int s0 = (int)(rc.x & 0xFFFFu), s1 = (int)(rc.y & 0xFFFFu);
        int s2 = (int)(rc.z & 0xFFFFu), s3 = (int)(rc.w & 0xFFFFu);
        unsigned p0 = cnt32[s0], p1 = cnt32[s1], p2 = cnt32[s2], p3 = cnt32[s3];
        unsigned x0 = xbu[(size_t)s0 * 64 + lane];
        unsigned x1 = xbu[(size_t)s1 * 64 + lane];
        unsigned x2 = xbu[(size_t)s2 * 64 + lane];
        unsigned x3 = xbu[(size_t)s3 * 64 + lane];
        float v0 = (float)(rc.x >> 16) * (1.0f / 65536.0f) * rsqrtf(degof(p0));
        float v1 = (float)(rc.y >> 16) * (1.0f / 65536.0f) * rsqrtf(degof(p1));
        float v2 = (float)(rc.z >> 16) * (1.0f / 65536.0f) * rsqrtf(degof(p2));
        float v3 = (float)(rc.w >> 16) * (1.0f / 65536.0f) * rsqrtf(degof(p3));
        ax += v0 * bflo(x0) + v1 * bflo(x1) + v2 * bflo(x2) + v3 * bflo(x3);
        ay += v0 * bfhi(x0) + v1 * bfhi(x1) + v2 * bfhi(x2) + v3 * bfhi(x3);
    }
    for (; k < n; ++k) {
        unsigned r0 = eb[k];
        int s0 = (int)(r0 & 0xFFFFu);
        unsigned p0 = cnt32[s0];
        unsigned x0 = xbu[(size_t)s0 * 64 + lane];
        float v0 = (float)(r0 >> 16) * (1.0f / 65536.0f) * rsqrtf(degof(p0));
        ax += v0 * bflo(x0); ay += v0 * bfhi(x0);
    }
    aggu[(size_t)node * 64 + lane] =
        (unsigned)f2bf(ax * s) | ((unsigned)f2bf(ay * s) << 16);
}

// ------- fused dual MFMA GEMM: out = relu(agg @ Wbt^T) @ Wlbt^T + bias -------
__global__ __launch_bounds__(256) void fused_gemm(
    const short* __restrict__ agg, const short* __restrict__ Wbt,
    const short* __restrict__ Wlbt, const float* __restrict__ bias,
    float* __restrict__ out)
{
    __shared__ __align__(16) short Bs1[DD * DD];  // Wbt [col][k], 32KB, swizzled
    __shared__ __align__(16) short Bs2[DD * DD];  // Wlbt [col][k], 32KB, swizzled
    __shared__ __align__(16) short As[64 * DD];   // A tile / relu(h) tile, 16KB
    const int t = threadIdx.x;
    const int i0 = blockIdx.x * 64;

    // stage Bs1/Bs2 (bf16 straight copies, swizzled)
    for (int u = t; u < 2048; u += 256) {
        int byte = u << 4;
        int brow = byte >> 8;
        int sw = byte ^ ((brow & 7) << 4);
        *(short8*)((char*)Bs1 + sw) = *(const short8*)((const char*)Wbt + byte);
        *(short8*)((char*)Bs2 + sw) = *(const short8*)((const char*)Wlbt + byte);
    }
    // stage A tile from agg (bf16 straight copy, swizzled; zero-pad tail rows)
    for (int u = t; u < 1024; u += 256) {
        int arow = u >> 4;
        int kc = (u & 15) << 3;
        int grow = i0 + arow;
        short8 v;
#pragma unroll
        for (int i = 0; i < 8; ++i) v[i] = 0;
        if (grow < NN)
            v = *(const short8*)(agg + (size_t)grow * DD + kc);
        int byte = (arow << 8) + (kc << 1);
        *(short8*)((char*)As + (byte ^ ((arow & 7) << 4))) = v;
    }
    __syncthreads();

    const int lane = t & 63, wv = t >> 6;
    const int c0 = lane & 15, g = lane >> 4;
    const int arow = wv * 16 + c0;
    f32x4 acc[8];
#pragma unroll
    for (int n = 0; n < 8; ++n) { acc[n][0] = acc[n][1] = acc[n][2] = acc[n][3] = 0.f; }

    // GEMM1: h = A @ Wbt^T
#pragma unroll
    for (int s = 0; s < 4; ++s) {
        int k0 = s * 32 + g * 8;
        int abyte = (arow << 8) + (k0 << 1);
        bf16x8 a = *(const bf16x8*)((const char*)As + (abyte ^ ((arow & 7) << 4)));
#pragma unroll
        for (int n = 0; n < 8; ++n) {
            int bcol = n * 16 + c0;
            int bbyte = (bcol << 8) + (k0 << 1);
            bf16x8 b = *(const bf16x8*)((const char*)Bs1 + (bbyte ^ ((bcol & 7) << 4)));
            acc[n] = __builtin_amdgcn_mfma_f32_16x16x32_bf16(a, b, acc[n], 0, 0, 0);
        }
    }
    __syncthreads();   // all GEMM1 LDS reads done before As overwrite

    // write relu(h) back into As as bf16 (C/D layout: col=c0+16n, row=wv*16+g*4+r)
#pragma unroll
    for (int n = 0; n < 8; ++n) {
        int ccol = n * 16 + c0;
#pragma unroll
        for (int r = 0; r < 4; ++r) {
            int hrow = wv * 16 + g * 4 + r;
            int byte = (hrow << 8) + (ccol << 1);
            *(unsigned short*)((char*)As + (byte ^ ((hrow & 7) << 4))) =
                f2bf(fmaxf(acc[n][r], 0.f));
        }
    }
    __syncthreads();

#pragma unroll
    for (int n = 0; n < 8; ++n) { acc[n][0] = acc[n][1] = acc[n][2] = acc[n][3] = 0.f; }

    // GEMM2: out = relu(h) @ Wlbt^T
#pragma unroll
    for (int s = 0; s < 4; ++s) {
        int k0 = s * 32 + g * 8;
        int abyte = (arow << 8) + (k0 << 1);
        bf16x8 a = *(const bf16x8*)((const char*)As + (abyte ^ ((arow & 7) << 4)));
#pragma unroll
        for (int n = 0; n < 8; ++n) {
            int bcol = n * 16 + c0;
            int bbyte = (bcol << 8) + (k0 << 1);
            bf16x8 b = *(const bf16x8*)((const char*)Bs2 + (bbyte ^ ((bcol & 7) << 4)));
            acc[n] = __builtin_amdgcn_mfma_f32_16x16x32_bf16(a, b, acc[n], 0, 0, 0);
        }
    }

    // store with bias
#pragma unroll
    for (int n = 0; n < 8; ++n) {
        int ccol = n * 16 + c0;
        float bb = bias[ccol];
#pragma unroll
        for (int r = 0; r < 4; ++r) {
            int grow = i0 + wv * 16 + g * 4 + r;
            if (grow < NN)
                out[(size_t)grow * DD + ccol] = acc[n][r] + bb;
        }
    }
}

extern "C" void kernel_launch(void* const* d_in, const int* in_sizes, int n_in,
                              void* d_out, int out_size, void* d_ws, size_t ws_size,
                              hipStream_t stream)
{
    const float* x    = (const float*)d_in[0];
    const int*   ei   = (const int*)d_in[1];
    const float* ew   = (const float*)d_in[2];
    const float* W0   = (const float*)d_in[3];
    const float* w_ih = (const float*)d_in[4];
    const float* w_hh = (const float*)d_in[5];
    const float* b_ih = (const float*)d_in[6];
    const float* b_hh = (const float*)d_in[7];
    const float* Wlin = (const float*)d_in[8];
    const float* blin = (const float*)d_in[9];
    float* out = (float*)d_out;

    const int* row = ei;        // source
    const int* col = ei + EE;   // target

    // workspace (bytes):
    // Wbt[32768] | Wlbt[32768] | cnt32[200704] | xb[12.8MB] | agg[12.8MB] | edges[9.6MB]
    char* ws = (char*)d_ws;
    unsigned short* Wbt  = (unsigned short*)ws;
    unsigned short* Wlbt = (unsigned short*)(ws + 32768);
    unsigned* cnt32 = (unsigned*)(ws + 65536);
    short* xb   = (short*)(ws + 266240);
    short* agg  = (short*)(ws + 13066240);
    unsigned* edges = (unsigned*)(ws + 25866240);

    init_kernel<<<3302, 256, 0, stream>>>(cnt32, W0, w_ih, w_hh, b_ih, b_hh,
                                          Wbt, Wlin, Wlbt, x, xb);

    histfill_kernel<<<(EE + 255) / 256, 256, 0, stream>>>(row, col, ew, cnt32, edges);

    gather_kernel<<<(NN + 3) / 4, 256, 0, stream>>>(
        edges, cnt32, (const unsigned*)xb, (unsigned*)agg);

    fused_gemm<<<(NN + 63) / 64, 256, 0, stream>>>(
        agg, (const short*)Wbt, (const short*)Wlbt, blin, out);
}